// Round 4
// baseline (819.303 us; speedup 1.0000x reference)
//
#include <hip/hip_runtime.h>

typedef _Float16 f16;
typedef _Float16 f16x8 __attribute__((ext_vector_type(8)));
typedef _Float16 f16x4 __attribute__((ext_vector_type(4)));
typedef float    f32x4 __attribute__((ext_vector_type(4)));

static constexpr int H   = 128;   // hidden width
static constexpr int MT  = 128;   // edges per block
static constexpr int WCH = 4096;  // halves per W chunk (128 n x 32 k)
static constexpr int NCH = 20;    // 12 (W0) + 4 (W1) + 4 (W2)
static constexpr size_t WS_NEED = (size_t)NCH * WCH * sizeof(f16);  // 163840 B

// -------- W pre-conversion: f32 row-major [K][128] -> f16 swizzled chunk image --------
// element (n, k) of chunk cid lives at ws[cid*4096 + n*32 + ((k>>3) ^ ((n>>2)&3))*8 + (k&7)]
__global__ __launch_bounds__(256)
void wprep(const float* __restrict__ W0, const float* __restrict__ W1,
           const float* __restrict__ W2, f16* __restrict__ ws)
{
    int e = blockIdx.x * 256 + threadIdx.x;
    if (e >= NCH * WCH) return;
    int cid = e >> 12;
    int rem = e & 4095;
    int k   = rem >> 7;     // 0..31
    int n   = rem & 127;    // fastest -> coalesced W reads
    const float* W; int k0;
    if (cid < 12)      { W = W0; k0 = cid * 32; }
    else if (cid < 16) { W = W1; k0 = (cid - 12) * 32; }
    else               { W = W2; k0 = (cid - 16) * 32; }
    f16 v = (f16)W[(size_t)(k0 + k) * H + n];
    int su = (k >> 3) ^ ((n >> 2) & 3);
    ws[cid * WCH + n * 32 + su * 8 + (k & 7)] = v;
}

__device__ __forceinline__ void glds16(const f16* g, f16* l) {
    __builtin_amdgcn_global_load_lds((const __attribute__((address_space(1))) void*)g,
                                     (__attribute__((address_space(3))) void*)l, 16, 0, 0);
}

template <int WPRE>
__global__ __launch_bounds__(256, 2)
void edge_mlp_fused(const float* __restrict__ x,
                    const int* __restrict__ eidx,
                    const float* __restrict__ edge,
                    const f16* __restrict__ wpre,
                    const float* __restrict__ W0, const float* __restrict__ b0,
                    const float* __restrict__ g0, const float* __restrict__ be0,
                    const float* __restrict__ W1, const float* __restrict__ b1,
                    const float* __restrict__ g1, const float* __restrict__ be1,
                    const float* __restrict__ W2, const float* __restrict__ b2,
                    const float* __restrict__ g2, const float* __restrict__ be2,
                    const float* __restrict__ W3, const float* __restrict__ b3,
                    float* __restrict__ out, int E)
{
    // double-buffered W tile: 128 n x 32 k halves each, swizzled
    __shared__ __align__(16) f16 wch[2 * WCH];    // 16384 B
    // inter-layer activations, swizzled, wave-private rows
    __shared__ __align__(16) f16 act[MT * H];     // 32768 B
    // total 49152 B -> 3 blocks/CU (if regs allow)

    const int tid  = threadIdx.x;
    const int lane = tid & 63;
    const int wid  = tid >> 6;
    const int c    = lane & 15;   // MFMA 16-dim lane coord
    const int g    = lane >> 4;   // quad group 0..3
    const int wrow = wid * 32;
    const long long e0 = (long long)blockIdx.x * MT;

    // A gather pointers: lane (c,g) owns rows wrow+c and wrow+16+c
    long long er0 = e0 + wrow + c;      if (er0 >= E) er0 = (long long)E - 1;
    long long er1 = e0 + wrow + 16 + c; if (er1 >= E) er1 = (long long)E - 1;
    const float* ps0 = x    + (size_t)eidx[er0]     * H;
    const float* ps1 = x    + (size_t)eidx[er1]     * H;
    const float* pd0 = x    + (size_t)eidx[E + er0] * H;
    const float* pd1 = x    + (size_t)eidx[E + er1] * H;
    const float* pe0 = edge + (size_t)er0           * H;
    const float* pe1 = edge + (size_t)er1           * H;

    f32x4 acc[8][2];
    #pragma unroll
    for (int t = 0; t < 8; ++t) {
        acc[t][0] = f32x4{0.f, 0.f, 0.f, 0.f};
        acc[t][1] = f32x4{0.f, 0.f, 0.f, 0.f};
    }

    // ---- depth-1 A prefetch: MFMA fragments straight from global (16 VGPR) ----
    float4 apf0, apf1, apf2, apf3;
    auto issueA = [&](int kc) {
        const float* q0 = ((kc < 4) ? ps0 : (kc < 8) ? pd0 : pe0) + (kc & 3) * 32 + g * 8;
        const float* q1 = ((kc < 4) ? ps1 : (kc < 8) ? pd1 : pe1) + (kc & 3) * 32 + g * 8;
        apf0 = ((const float4*)q0)[0]; apf1 = ((const float4*)q0)[1];
        apf2 = ((const float4*)q1)[0]; apf3 = ((const float4*)q1)[1];
    };
    auto cvtA = [&](f16x8& a0, f16x8& a1) {
        a0[0] = (f16)apf0.x; a0[1] = (f16)apf0.y; a0[2] = (f16)apf0.z; a0[3] = (f16)apf0.w;
        a0[4] = (f16)apf1.x; a0[5] = (f16)apf1.y; a0[6] = (f16)apf1.z; a0[7] = (f16)apf1.w;
        a1[0] = (f16)apf2.x; a1[1] = (f16)apf2.y; a1[2] = (f16)apf2.z; a1[3] = (f16)apf2.w;
        a1[4] = (f16)apf3.x; a1[5] = (f16)apf3.y; a1[6] = (f16)apf3.z; a1[7] = (f16)apf3.w;
    };

    // stage W chunk cid into wchunk buffer pbuf (visible after next __syncthreads)
    auto stageW = [&](int cid, int pbuf) {
        f16* dst = &wch[pbuf * WCH];
        if (WPRE) {
            const f16* src = wpre + (size_t)cid * WCH + wid * 1024;  // wave covers 2 KB
            f16* d = dst + wid * 1024;                               // wave-uniform LDS base
            glds16(src + (lane << 3), d);                            // lanes fill d + lane*16B
            glds16(src + 512 + (lane << 3), d + 512);
        } else {
            const float* W = (cid < 12) ? W0 : (cid < 16) ? W1 : W2;
            int k0 = ((cid < 12) ? cid : (cid < 16) ? (cid - 12) : (cid - 16)) * 32;
            #pragma unroll
            for (int i = 0; i < 4; ++i) {
                int f  = i * 256 + tid;
                int n  = f & 127;
                int kq = f >> 7;   // 0..7
                const float* pw = W + (size_t)(k0 + kq * 4) * H + n;
                f16x4 v;
                v[0] = (f16)pw[0]; v[1] = (f16)pw[H]; v[2] = (f16)pw[2 * H]; v[3] = (f16)pw[3 * H];
                int su = (kq >> 1) ^ ((n >> 2) & 3);
                *(f16x4*)&dst[n * 32 + su * 8 + (kq & 1) * 4] = v;
            }
        }
    };

    const int sw = (g ^ ((c >> 2) & 3)) * 8;   // W read-side swizzle (halves)

    // one K=32 step, A fragments in registers
    auto mfma_reg = [&](f16x8 a0, f16x8 a1, int pbuf) {
        const f16* wb = &wch[pbuf * WCH];
        #pragma unroll
        for (int t = 0; t < 8; ++t) {
            f16x8 bf = *(const f16x8*)&wb[(t * 16 + c) * 32 + sw];
            acc[t][0] = __builtin_amdgcn_mfma_f32_16x16x32_f16(a0, bf, acc[t][0], 0, 0, 0);
            acc[t][1] = __builtin_amdgcn_mfma_f32_16x16x32_f16(a1, bf, acc[t][1], 0, 0, 0);
        }
    };
    // one K=32 step, A from act (swizzled; rows wrow+c / wrow+16+c are wave-private)
    auto mfma_act = [&](int koff, int pbuf) {
        const f16* wb = &wch[pbuf * WCH];
        int col = (koff + g * 8) ^ (c << 3);   // row&15 == c for both read rows
        f16x8 a0 = *(const f16x8*)&act[(wrow + c) * H + col];
        f16x8 a1 = *(const f16x8*)&act[(wrow + 16 + c) * H + col];
        #pragma unroll
        for (int t = 0; t < 8; ++t) {
            f16x8 bf = *(const f16x8*)&wb[(t * 16 + c) * 32 + sw];
            acc[t][0] = __builtin_amdgcn_mfma_f32_16x16x32_f16(a0, bf, acc[t][0], 0, 0, 0);
            acc[t][1] = __builtin_amdgcn_mfma_f32_16x16x32_f16(a1, bf, acc[t][1], 0, 0, 0);
        }
    };

    // LN(+bias,gamma,beta)+ReLU on acc -> act (swizzled rows, wave-private), reset acc
    auto ln_relu_store = [&](const float* __restrict__ bias,
                             const float* __restrict__ gamma,
                             const float* __restrict__ beta) {
        float mu[2][4], rs[2][4];
        #pragma unroll
        for (int t = 0; t < 8; ++t) {
            float bt = bias[t * 16 + c];
            #pragma unroll
            for (int s = 0; s < 2; ++s)
                #pragma unroll
                for (int r = 0; r < 4; ++r) acc[t][s][r] += bt;
        }
        #pragma unroll
        for (int s = 0; s < 2; ++s)
            #pragma unroll
            for (int r = 0; r < 4; ++r) {
                float v = 0.f, q = 0.f;
                #pragma unroll
                for (int t = 0; t < 8; ++t) { float a = acc[t][s][r]; v += a; q += a * a; }
                #pragma unroll
                for (int m = 1; m < 16; m <<= 1) {
                    v += __shfl_xor(v, m, 64);
                    q += __shfl_xor(q, m, 64);
                }
                float mean = v * (1.0f / H);
                float var  = q * (1.0f / H) - mean * mean;
                mu[s][r] = mean;
                rs[s][r] = rsqrtf(var + 1e-5f);
            }
        #pragma unroll
        for (int t = 0; t < 8; ++t) {
            float gm = gamma[t * 16 + c];
            float bb = beta[t * 16 + c];
            #pragma unroll
            for (int s = 0; s < 2; ++s)
                #pragma unroll
                for (int r = 0; r < 4; ++r) {
                    float v = (acc[t][s][r] - mu[s][r]) * rs[s][r] * gm + bb;
                    v = fmaxf(v, 0.f);
                    int row = wrow + s * 16 + g * 4 + r;
                    act[row * H + ((t * 16 + c) ^ ((row & 15) << 3))] = (f16)v;
                }
        }
        #pragma unroll
        for (int t = 0; t < 8; ++t) {
            acc[t][0] = f32x4{0.f, 0.f, 0.f, 0.f};
            acc[t][1] = f32x4{0.f, 0.f, 0.f, 0.f};
        }
    };

    // ---------------- prologue ----------------
    stageW(0, 0);
    issueA(0);
    __syncthreads();   // W chunk 0 visible; A(0) loads complete (values in regs)

    // ---------------- GEMM1: concat(x[src],x[dst],edge) @ W0, K=384 ----------------
    #pragma unroll 2
    for (int kc = 0; kc < 12; ++kc) {
        f16x8 a0, a1;
        cvtA(a0, a1);                    // consume apf(kc) before reuse
        if (kc < 11) issueA(kc + 1);
        stageW(kc + 1, (kc + 1) & 1);    // kc==11 pre-stages W1 chunk 0 (cid 12)
        mfma_reg(a0, a1, kc & 1);
        __syncthreads();                 // staged chunk visible; read buffer retired
    }
    ln_relu_store(b0, g0, be0);

    // ---------------- GEMM2: act @ W1, K=128 ----------------
    #pragma unroll 2
    for (int kc = 0; kc < 4; ++kc) {
        stageW(13 + kc, (kc + 1) & 1);   // W1 chunks 1..3, then W2 chunk 0 (cid 16)
        mfma_act(kc * 32, kc & 1);
        __syncthreads();
    }
    ln_relu_store(b1, g1, be1);

    // ---------------- GEMM3: act @ W2, K=128 ----------------
    #pragma unroll 2
    for (int kc = 0; kc < 4; ++kc) {
        if (kc < 3) stageW(17 + kc, (kc + 1) & 1);
        mfma_act(kc * 32, kc & 1);
        if (kc < 3) __syncthreads();
    }

    // ---------------- layer-3 LN+ReLU fused with final dot(W3)+b3 ----------------
    {
        float mu[2][4], rs[2][4];
        #pragma unroll
        for (int t = 0; t < 8; ++t) {
            float bt = b2[t * 16 + c];
            #pragma unroll
            for (int s = 0; s < 2; ++s)
                #pragma unroll
                for (int r = 0; r < 4; ++r) acc[t][s][r] += bt;
        }
        #pragma unroll
        for (int s = 0; s < 2; ++s)
            #pragma unroll
            for (int r = 0; r < 4; ++r) {
                float v = 0.f, q = 0.f;
                #pragma unroll
                for (int t = 0; t < 8; ++t) { float a = acc[t][s][r]; v += a; q += a * a; }
                #pragma unroll
                for (int m = 1; m < 16; m <<= 1) {
                    v += __shfl_xor(v, m, 64);
                    q += __shfl_xor(q, m, 64);
                }
                float mean = v * (1.0f / H);
                float var  = q * (1.0f / H) - mean * mean;
                mu[s][r] = mean;
                rs[s][r] = rsqrtf(var + 1e-5f);
            }
        float po[2][4] = {{0.f,0.f,0.f,0.f},{0.f,0.f,0.f,0.f}};
        #pragma unroll
        for (int t = 0; t < 8; ++t) {
            float gm  = g2[t * 16 + c];
            float bb  = be2[t * 16 + c];
            float w3v = W3[t * 16 + c];
            #pragma unroll
            for (int s = 0; s < 2; ++s)
                #pragma unroll
                for (int r = 0; r < 4; ++r) {
                    float v = (acc[t][s][r] - mu[s][r]) * rs[s][r] * gm + bb;
                    v = fmaxf(v, 0.f);
                    po[s][r] += v * w3v;
                }
        }
        #pragma unroll
        for (int s = 0; s < 2; ++s)
            #pragma unroll
            for (int r = 0; r < 4; ++r) {
                #pragma unroll
                for (int m = 1; m < 16; m <<= 1) po[s][r] += __shfl_xor(po[s][r], m, 64);
            }
        if (c == 0) {
            float bb3 = b3[0];
            #pragma unroll
            for (int s = 0; s < 2; ++s) {
                long long eb = e0 + wrow + s * 16 + g * 4;
                if (eb + 3 < E) {
                    float4 o;
                    o.x = po[s][0] + bb3; o.y = po[s][1] + bb3;
                    o.z = po[s][2] + bb3; o.w = po[s][3] + bb3;
                    *(float4*)(out + eb) = o;
                } else {
                    #pragma unroll
                    for (int r = 0; r < 4; ++r)
                        if (eb + r < E) out[eb + r] = po[s][r] + bb3;
                }
            }
        }
    }
}

extern "C" void kernel_launch(void* const* d_in, const int* in_sizes, int n_in,
                              void* d_out, int out_size, void* d_ws, size_t ws_size,
                              hipStream_t stream)
{
    const float* x    = (const float*)d_in[0];
    const int*   eidx = (const int*)d_in[1];     // int64 in reference -> int32 on device
    const float* edge = (const float*)d_in[2];
    const float* W0   = (const float*)d_in[3];
    const float* b0   = (const float*)d_in[4];
    const float* g0   = (const float*)d_in[5];
    const float* be0  = (const float*)d_in[6];
    const float* W1   = (const float*)d_in[7];
    const float* b1   = (const float*)d_in[8];
    const float* g1   = (const float*)d_in[9];
    const float* be1  = (const float*)d_in[10];
    const float* W2   = (const float*)d_in[11];
    const float* b2   = (const float*)d_in[12];
    const float* g2   = (const float*)d_in[13];
    const float* be2  = (const float*)d_in[14];
    const float* W3   = (const float*)d_in[15];
    const float* b3   = (const float*)d_in[16];
    float*       out  = (float*)d_out;

    const int E = in_sizes[1] / 2;           // edge_index is (2, E)
    const int grid = (E + MT - 1) / MT;

    if (d_ws && ws_size >= WS_NEED) {
        f16* wsp = (f16*)d_ws;
        hipLaunchKernelGGL(wprep, dim3((NCH * WCH + 255) / 256), dim3(256), 0, stream,
                           W0, W1, W2, wsp);
        hipLaunchKernelGGL((edge_mlp_fused<1>), dim3(grid), dim3(256), 0, stream,
                           x, eidx, edge, (const f16*)wsp,
                           W0, b0, g0, be0, W1, b1, g1, be1, W2, b2, g2, be2,
                           W3, b3, out, E);
    } else {
        hipLaunchKernelGGL((edge_mlp_fused<0>), dim3(grid), dim3(256), 0, stream,
                           x, eidx, edge, (const f16*)nullptr,
                           W0, b0, g0, be0, W1, b1, g1, be1, W2, b2, g2, be2,
                           W3, b3, out, E);
    }
}